// Round 4
// baseline (277.809 us; speedup 1.0000x reference)
//
#include <hip/hip_runtime.h>
#include <hip/hip_cooperative_groups.h>

namespace cg = cooperative_groups;

// ---------------------------------------------------------------------------
// Predictor, fused cooperative version.
//   One kernel: LDS-staged patch classification (R2 structure — wave-dense
//   coalesced loads; R3's per-lane 144B-stride thrashed L1), per-thread
//   results held in registers (2-bit codes + center values), grid sync,
//   block-0 f64 reduction, grid sync, in-register fixup, single out write.
//   Traffic: 302 MB read + 16.8 MB write (phase2 re-read + extra launches gone).
// Fallback: if cooperative launch is rejected, run the proven 3-kernel path.
// ---------------------------------------------------------------------------

struct Partial { float sb, sw; unsigned int cb, cw; };          // 16 B
struct Acc     { double sumB, sumW; unsigned int cntB, cntW; };

#define NBLKC  1024   // cooperative grid: 4 blocks/CU, co-residency-safe
#define CHUNKS 16     // 256 patches per chunk -> 4096 patches per block

// per-patch classify: returns code 0/1/2, sets value = center
__device__ __forceinline__ int classify(const float* ip, const float* ep, float& value) {
    float xd[9], xa[9];
    int cd = 0, ca = 0;
#pragma unroll
    for (int k = 0; k < 9; ++k) {
        float e = ep[k], v = ip[k];
        bool dis = e > 0.5f;
        bool ac  = (e != 0.0f) && !dis;
        xd[k] = dis ? v : 0.0f;
        xa[k] = ac  ? v : 0.0f;
        cd += dis ? 1 : 0;
        ca += ac  ? 1 : 0;
    }
    // numpy pairwise order for 9-element f32 row sum
    float sd = ((xd[0] + xd[1]) + (xd[2] + xd[3])) + ((xd[4] + xd[5]) + (xd[6] + xd[7]));
    sd += xd[8];
    float sa = ((xa[0] + xa[1]) + (xa[2] + xa[3])) + ((xa[4] + xa[5]) + (xa[6] + xa[7]));
    sa += xa[8];
    // md > ma  <=>  sd*ca' > sa*cd'  (exact in f64; equals np's f64-div compare)
    const int cdm = cd > 0 ? cd : 1;
    const int cam = ca > 0 ? ca : 1;
    const bool gt = ((double)sd * (double)cam) > ((double)sa * (double)cdm);
    value = ip[4];
    return (cd > 0 && ca > 0) ? (gt ? 0 : 1) : 2;
}

__global__ __launch_bounds__(256, 4) void fused(const float* __restrict__ img,
                                                const float* __restrict__ edg,
                                                float* __restrict__ out,
                                                Partial* __restrict__ part,
                                                Acc* __restrict__ acc)
{
    __shared__ float s_img[256 * 9];
    __shared__ float s_edg[256 * 9];
    const int t = threadIdx.x;

    float val[CHUNKS];
    unsigned int ocode = 0;
    float accB = 0.0f, accW = 0.0f;
    int   ncb = 0, ncw = 0;

#pragma unroll
    for (int c = 0; c < CHUNKS; ++c) {
        const size_t chunk = (size_t)blockIdx.x * CHUNKS + c;
        const size_t base  = chunk * (256 * 9);

        const float4* gi = reinterpret_cast<const float4*>(img + base);
        const float4* ge = reinterpret_cast<const float4*>(edg + base);
        float4* si = reinterpret_cast<float4*>(s_img);
        float4* se = reinterpret_cast<float4*>(s_edg);
        si[t]       = gi[t];       se[t]       = ge[t];
        si[t + 256] = gi[t + 256]; se[t + 256] = ge[t + 256];
        if (t < 64) { si[t + 512] = gi[t + 512]; se[t + 512] = ge[t + 512]; }
        __syncthreads();

        float v;
        int code = classify(s_img + 9 * t, s_edg + 9 * t, v);
        val[c] = v;
        ocode |= (unsigned)code << (2 * c);

        accB += (code == 0) ? v : 0.0f;
        accW += (code == 1) ? v : 0.0f;
        ncb  += (code == 0) ? 1 : 0;
        ncw  += (code == 1) ? 1 : 0;

        __syncthreads();  // LDS reused next chunk
    }

    // ---- block reduction into one partial ----
#pragma unroll
    for (int off = 32; off > 0; off >>= 1) {
        accB += __shfl_down(accB, off);
        accW += __shfl_down(accW, off);
        ncb  += __shfl_down(ncb, off);
        ncw  += __shfl_down(ncw, off);
    }
    {
        __shared__ float rb[4], rw[4];
        __shared__ unsigned int ub[4], uw[4];
        const int wave = t >> 6, lane = t & 63;
        if (lane == 0) { rb[wave] = accB; rw[wave] = accW; ub[wave] = ncb; uw[wave] = ncw; }
        __syncthreads();
        if (t == 0) {
            Partial p;
            p.sb = (rb[0] + rb[1]) + (rb[2] + rb[3]);
            p.sw = (rw[0] + rw[1]) + (rw[2] + rw[3]);
            p.cb = ub[0] + ub[1] + ub[2] + ub[3];
            p.cw = uw[0] + uw[1] + uw[2] + uw[3];
            part[blockIdx.x] = p;
        }
    }

    cg::this_grid().sync();

    // ---- block 0: final f64 reduction over 1024 partials ----
    if (blockIdx.x == 0) {
        double sb = 0.0, sw = 0.0;
        unsigned int cb = 0, cw = 0;
#pragma unroll
        for (int i = 0; i < NBLKC; i += 256) {
            Partial p = part[i + t];
            sb += (double)p.sb; sw += (double)p.sw; cb += p.cb; cw += p.cw;
        }
#pragma unroll
        for (int off = 32; off > 0; off >>= 1) {
            sb += __shfl_down(sb, off);
            sw += __shfl_down(sw, off);
            cb += __shfl_down(cb, off);
            cw += __shfl_down(cw, off);
        }
        __shared__ double db[4], dw[4];
        __shared__ unsigned int eb[4], ew[4];
        const int wave = t >> 6, lane = t & 63;
        if (lane == 0) { db[wave] = sb; dw[wave] = sw; eb[wave] = cb; ew[wave] = cw; }
        __syncthreads();
        if (t == 0) {
            Acc a;
            a.sumB = db[0] + db[1] + db[2] + db[3];
            a.sumW = dw[0] + dw[1] + dw[2] + dw[3];
            a.cntB = eb[0] + eb[1] + eb[2] + eb[3];
            a.cntW = ew[0] + ew[1] + ew[2] + ew[3];
            *acc = a;
        }
    }

    cg::this_grid().sync();

    const unsigned cb = acc->cntB, cw = acc->cntW;
    const double avgB = acc->sumB / (double)(cb ? cb : 1u);
    const double avgW = acc->sumW / (double)(cw ? cw : 1u);

    // ---- in-register fixup + single coalesced write ----
#pragma unroll
    for (int c = 0; c < CHUNKS; ++c) {
        const size_t chunk = (size_t)blockIdx.x * CHUNKS + c;
        const int code = (ocode >> (2 * c)) & 3;
        float o;
        if (code == 2) {
            const double v = (double)val[c];
            o = (fabs(v - avgB) < fabs(v - avgW)) ? 0.0f : 1.0f;
        } else {
            o = (float)code;
        }
        out[chunk * 256 + t] = o;
    }
}

// ------------------------- fallback: proven R2 path -------------------------

__global__ __launch_bounds__(256) void phase1(const float* __restrict__ img,
                                              const float* __restrict__ edg,
                                              float* __restrict__ out,
                                              Partial* __restrict__ part)
{
    __shared__ float s_img[256 * 9];
    __shared__ float s_edg[256 * 9];
    const int t = threadIdx.x;
    float accB = 0.0f, accW = 0.0f;
    int   ncb = 0, ncw = 0;

    for (int c = 0; c < 4; ++c) {
        const size_t chunk = (size_t)blockIdx.x * 4 + c;
        const size_t base  = chunk * (256 * 9);
        const float4* gi = reinterpret_cast<const float4*>(img + base);
        const float4* ge = reinterpret_cast<const float4*>(edg + base);
        float4* si = reinterpret_cast<float4*>(s_img);
        float4* se = reinterpret_cast<float4*>(s_edg);
        si[t]       = gi[t];       se[t]       = ge[t];
        si[t + 256] = gi[t + 256]; se[t + 256] = ge[t + 256];
        if (t < 64) { si[t + 512] = gi[t + 512]; se[t + 512] = ge[t + 512]; }
        __syncthreads();

        float v;
        int code = classify(s_img + 9 * t, s_edg + 9 * t, v);
        out[chunk * 256 + t] = (float)code;
        accB += (code == 0) ? v : 0.0f;
        accW += (code == 1) ? v : 0.0f;
        ncb  += (code == 0) ? 1 : 0;
        ncw  += (code == 1) ? 1 : 0;
        __syncthreads();
    }

#pragma unroll
    for (int off = 32; off > 0; off >>= 1) {
        accB += __shfl_down(accB, off);
        accW += __shfl_down(accW, off);
        ncb  += __shfl_down(ncb, off);
        ncw  += __shfl_down(ncw, off);
    }
    __shared__ float rb[4], rw[4];
    __shared__ unsigned int ub[4], uw[4];
    const int wave = t >> 6, lane = t & 63;
    if (lane == 0) { rb[wave] = accB; rw[wave] = accW; ub[wave] = ncb; uw[wave] = ncw; }
    __syncthreads();
    if (t == 0) {
        Partial p;
        p.sb = (rb[0] + rb[1]) + (rb[2] + rb[3]);
        p.sw = (rw[0] + rw[1]) + (rw[2] + rw[3]);
        p.cb = ub[0] + ub[1] + ub[2] + ub[3];
        p.cw = uw[0] + uw[1] + uw[2] + uw[3];
        part[blockIdx.x] = p;
    }
}

__global__ __launch_bounds__(256) void reduceK(const Partial* __restrict__ part,
                                               int n, Acc* __restrict__ acc)
{
    const int t = threadIdx.x;
    double sb = 0.0, sw = 0.0;
    unsigned int cb = 0, cw = 0;
    for (int i = t; i < n; i += 256) {
        Partial p = part[i];
        sb += (double)p.sb; sw += (double)p.sw; cb += p.cb; cw += p.cw;
    }
#pragma unroll
    for (int off = 32; off > 0; off >>= 1) {
        sb += __shfl_down(sb, off);
        sw += __shfl_down(sw, off);
        cb += __shfl_down(cb, off);
        cw += __shfl_down(cw, off);
    }
    __shared__ double db[4], dw[4];
    __shared__ unsigned int eb[4], ew[4];
    const int wave = t >> 6, lane = t & 63;
    if (lane == 0) { db[wave] = sb; dw[wave] = sw; eb[wave] = cb; ew[wave] = cw; }
    __syncthreads();
    if (t == 0) {
        Acc a;
        a.sumB = db[0] + db[1] + db[2] + db[3];
        a.sumW = dw[0] + dw[1] + dw[2] + dw[3];
        a.cntB = eb[0] + eb[1] + eb[2] + eb[3];
        a.cntW = ew[0] + ew[1] + ew[2] + ew[3];
        *acc = a;
    }
}

__global__ __launch_bounds__(256) void phase2(const float* __restrict__ img,
                                              float* __restrict__ out,
                                              const Acc* __restrict__ acc,
                                              int n4)
{
    const int i = blockIdx.x * 256 + threadIdx.x;
    if (i >= n4) return;
    float4 v = reinterpret_cast<const float4*>(out)[i];
    if (v.x == 2.0f || v.y == 2.0f || v.z == 2.0f || v.w == 2.0f) {
        const unsigned cb = acc->cntB, cw = acc->cntW;
        const double avgB = acc->sumB / (double)(cb ? cb : 1u);
        const double avgW = acc->sumW / (double)(cw ? cw : 1u);
        float r[4] = {v.x, v.y, v.z, v.w};
#pragma unroll
        for (int j = 0; j < 4; ++j) {
            if (r[j] == 2.0f) {
                const size_t p = (size_t)i * 4 + j;
                const double val = (double)img[p * 9 + 4];
                out[p] = (fabs(val - avgB) < fabs(val - avgW)) ? 0.0f : 1.0f;
            }
        }
    }
}

extern "C" void kernel_launch(void* const* d_in, const int* in_sizes, int n_in,
                              void* d_out, int out_size, void* d_ws, size_t ws_size,
                              hipStream_t stream) {
    const float* img = (const float*)d_in[0];
    const float* edg = (const float*)d_in[1];
    float* out = (float*)d_out;

    Partial* part = (Partial*)d_ws;                          // up to 4096*16 B
    Acc*     acc  = (Acc*)((char*)d_ws + 4096 * sizeof(Partial));

    const int N = in_sizes[0] / 9;                           // 4194304 patches

    void* args[] = { (void*)&img, (void*)&edg, (void*)&out, (void*)&part, (void*)&acc };
    hipError_t e = hipLaunchCooperativeKernel((const void*)fused, dim3(NBLKC), dim3(256),
                                              args, 0, stream);
    if (e != hipSuccess) {
        // fallback: proven 3-kernel path (deterministic; same numerics class)
        phase1<<<4096, 256, 0, stream>>>(img, edg, out, part);
        reduceK<<<1, 256, 0, stream>>>(part, 4096, acc);
        const int n4 = N / 4;
        phase2<<<(n4 + 255) / 256, 256, 0, stream>>>(img, out, acc, n4);
    }
}